// Round 13
// baseline (20.498 us; speedup 1.0000x reference)
//
#include <hip/hip_runtime.h>
#include <stdint.h>

// ACOLayer: reproduce JAX's sampling exactly.
//   u = jax.random.uniform(key(42), (32, 4096, 16), f32)
//   idx[b,i,a] = searchsorted(cdf_row_i, u[b,i,a]) clamped; -1 where a >= x[b,i]
// RNG: jax_threefry_partitionable=True stream:
//   bits[i] = o0 ^ o1, (o0,o1) = threefry2x32(key=(0,42), counter=(0, i))
//   u = bitcast((bits>>9)|0x3f800000) - 1.0f
// Search: unnormalized cumsum, target u*total; interpolation-start window
// +-64 with verified bracket + exact full-range fallback (round 11).
//
// Round 13 = round 12 with the LDS PADDING REMOVED (linear cdf):
//  - R8 measured padding at +2% when the search probed power-of-2 strides;
//    the interpolation search's probes are u*N-centered = random across
//    lanes, so padding now protects nothing.
//  - write-back becomes 4x ds_write_b128 (48 cyc/wave vs 93 for 16 b32)
//  - ~35 padi VALU ops per thread deleted
// Confirmed lever: DS instruction volume (R11: -13 reads -> -1.0 us).

#define N_IN    4096
#define N_OUT   4096
#define BS      32
#define MAX_A   16
#define THREADS 256
#define HALF    1048576u  /* 16 * N_IN * MAX_A */
#define WIN     64        /* half-width of interpolation window */

__device__ __forceinline__ uint32_t rotl32(uint32_t x, uint32_t r) {
    return (x << r) | (x >> (32u - r));
}

// Threefry-2x32, 20 rounds, key (0, 42) — jax.random.key(42)
__device__ __forceinline__ void threefry2x32_42(uint32_t x0, uint32_t x1,
                                                uint32_t& o0, uint32_t& o1) {
    const uint32_t k0 = 0u, k1 = 42u;
    const uint32_t k2 = k0 ^ k1 ^ 0x1BD11BDAu;
    x0 += k0; x1 += k1;
#define TF_R(r) { x0 += x1; x1 = rotl32(x1, (r)); x1 ^= x0; }
    TF_R(13) TF_R(15) TF_R(26) TF_R(6)
    x0 += k1; x1 += k2 + 1u;
    TF_R(17) TF_R(29) TF_R(16) TF_R(24)
    x0 += k2; x1 += k0 + 2u;
    TF_R(13) TF_R(15) TF_R(26) TF_R(6)
    x0 += k0; x1 += k1 + 3u;
    TF_R(17) TF_R(29) TF_R(16) TF_R(24)
    x0 += k1; x1 += k2 + 4u;
    TF_R(13) TF_R(15) TF_R(26) TF_R(6)
    x0 += k2; x1 += k0 + 5u;
#undef TF_R
    o0 = x0; o1 = x1;
}

__device__ __forceinline__ float bits_to_uniform(uint32_t b) {
    uint32_t f = (b >> 9) | 0x3f800000u;
    float r;
    __builtin_memcpy(&r, &f, 4);
    return r - 1.0f;
}

__global__ __launch_bounds__(THREADS, 8)
void aco_sample_kernel(const int* __restrict__ x,
                       const float* __restrict__ w,
                       int* __restrict__ out) {
    __shared__ __align__(16) float cdf[N_OUT];   // linear, 16 KB
    __shared__ float wsum[4];
    __shared__ int   xc[BS];

    const int row  = blockIdx.x;
    const int t    = threadIdx.x;
    const int lane = t & 63;
    const int wid  = t >> 6;

    // ---- stage 16 weights directly into registers (4x float4) ----
    const float4* wrow = (const float4*)(w + (size_t)row * N_OUT);
    float4 v0 = wrow[t * 4 + 0];
    float4 v1 = wrow[t * 4 + 1];
    float4 v2 = wrow[t * 4 + 2];
    float4 v3 = wrow[t * 4 + 3];

    if (t < BS) xc[t] = x[t * N_IN + row];

    // ---- threefry in the global-load-wait shadow (no memory deps) ----
    const int bb = t >> 4;
    const int aa = t & 15;
    const uint32_t j0 = (uint32_t)(bb * (N_IN * MAX_A) + row * MAX_A + aa);
    const uint32_t j1 = j0 + HALF;
    uint32_t o0, o1, p0, p1;
    threefry2x32_42(0u, j0, o0, o1);
    threefry2x32_42(0u, j1, p0, p1);
    const float u0 = bits_to_uniform(o0 ^ o1);
    const float u1 = bits_to_uniform(p0 ^ p1);

    // ---- per-thread total (no loc array -> low VGPR) ----
    float s = 0.f;
    s += v0.x; s += v0.y; s += v0.z; s += v0.w;
    s += v1.x; s += v1.y; s += v1.z; s += v1.w;
    s += v2.x; s += v2.y; s += v2.z; s += v2.w;
    s += v3.x; s += v3.y; s += v3.z; s += v3.w;
    const float my_total = s;

    // ---- wave-level inclusive scan of per-thread totals ----
    float incl = my_total;
    #pragma unroll
    for (int d = 1; d < 64; d <<= 1) {
        float n = __shfl_up(incl, d, 64);
        if (lane >= d) incl += n;
    }
    if (lane == 63) wsum[wid] = incl;
    __syncthreads();   // B1: wsum visible

    const float4 ws = *(const float4*)wsum;
    const float total = ws.x + ws.y + ws.z + ws.w;
    float wprefix = 0.f;
    if (wid > 0) wprefix += ws.x;
    if (wid > 1) wprefix += ws.y;
    if (wid > 2) wprefix += ws.z;
    const float chunk_prefix = wprefix + incl - my_total;

    // ---- write cumsum as 4x ds_write_b128 (running sums recomputed) ----
    {
        float4* c4 = (float4*)cdf + 4 * t;
        float r = chunk_prefix;
        float4 c;
        r += v0.x; c.x = r; r += v0.y; c.y = r;
        r += v0.z; c.z = r; r += v0.w; c.w = r;  c4[0] = c;
        r += v1.x; c.x = r; r += v1.y; c.y = r;
        r += v1.z; c.z = r; r += v1.w; c.w = r;  c4[1] = c;
        r += v2.x; c.x = r; r += v2.y; c.y = r;
        r += v2.z; c.z = r; r += v2.w; c.w = r;  c4[2] = c;
        r += v3.x; c.x = r; r += v3.y; c.y = r;
        r += v3.z; c.z = r; r += v3.w; c.w = r;  c4[3] = c;
    }
    __syncthreads();   // B2: full cdf visible

    const float t0 = u0 * total;
    const float t1 = u1 * total;

    // ---- interpolation-start windows ----
    const int i0 = (int)(u0 * (float)N_OUT);
    const int i1 = (int)(u1 * (float)N_OUT);
    int lo0 = i0 - WIN; if (lo0 < 0) lo0 = 0;
    int hi0 = i0 + WIN; if (hi0 > N_OUT) hi0 = N_OUT;
    int lo1 = i1 - WIN; if (lo1 < 0) lo1 = 0;
    int hi1 = i1 + WIN; if (hi1 > N_OUT) hi1 = N_OUT;

    // bracket verification (2 reads per draw)
    const bool ok0 = (lo0 == 0     || cdf[lo0 - 1] <  t0) &&
                     (hi0 == N_OUT || cdf[hi0 - 1] >= t0);
    const bool ok1 = (lo1 == 0     || cdf[lo1 - 1] <  t1) &&
                     (hi1 == N_OUT || cdf[hi1 - 1] >= t1);

    if (ok0 && ok1) {
        // window <= 128 -> 7 fused dual steps
        #pragma unroll
        for (int it = 0; it < 7; ++it) {
            const int m0 = (lo0 + hi0) >> 1;
            const int m1 = (lo1 + hi1) >> 1;
            const float f0 = cdf[m0];   // independent probes: MLP = 2
            const float f1 = cdf[m1];
            if (f0 < t0) lo0 = m0 + 1; else hi0 = m0;
            if (f1 < t1) lo1 = m1 + 1; else hi1 = m1;
        }
    } else {
        // exact full-range fallback (rare: ~6% of waves)
        lo0 = 0; hi0 = N_OUT; lo1 = 0; hi1 = N_OUT;
        #pragma unroll
        for (int it = 0; it < 12; ++it) {
            const int m0 = (lo0 + hi0) >> 1;
            const int m1 = (lo1 + hi1) >> 1;
            const float f0 = cdf[m0];
            const float f1 = cdf[m1];
            if (f0 < t0) lo0 = m0 + 1; else hi0 = m0;
            if (f1 < t1) lo1 = m1 + 1; else hi1 = m1;
        }
    }
    const int idx0 = lo0 < N_OUT ? lo0 : N_OUT - 1;
    const int idx1 = lo1 < N_OUT ? lo1 : N_OUT - 1;

    out[j0] = (aa < xc[bb])      ? idx0 : -1;
    out[j1] = (aa < xc[bb + 16]) ? idx1 : -1;
}

extern "C" void kernel_launch(void* const* d_in, const int* in_sizes, int n_in,
                              void* d_out, int out_size, void* d_ws, size_t ws_size,
                              hipStream_t stream) {
    // select inputs by size (robust to ordering):
    //   x: 32*4096 int32; weights: 4096*4096 f32
    const int*   x;
    const float* w;
    if (in_sizes[0] == BS * N_IN) { x = (const int*)d_in[0]; w = (const float*)d_in[1]; }
    else                          { x = (const int*)d_in[1]; w = (const float*)d_in[0]; }
    aco_sample_kernel<<<N_IN, THREADS, 0, stream>>>(x, w, (int*)d_out);
}